// Round 13
// baseline (2056.466 us; speedup 1.0000x reference)
//
#include <hip/hip_runtime.h>
#include <cmath>

// Memory_76957224010242: 100-step Adam inference loop.
// G = W^T W, u = (x-c)@W once; per-iter s = r@G fused with Adam + loss.
// R13: loop GEMM cloned from the measured-best gemm64 config (655 TF): 64x64
// tile, 256 thr / 4 waves, BK=64, 2-buf — with K-split 4 => 1024 blocks =
// 4 independent blocks/CU (inter-block latency hiding, the R12 gap). Splits
// write f32 partials (aliased onto dead Wt); separate vectorized k_adam sums
// partials + Adam + loss.

#define B_SZ 512
#define H_SZ 2048
#define D_SZ 4096
#define ITERS 100

typedef __attribute__((ext_vector_type(8))) short short8;
typedef __attribute__((ext_vector_type(4))) float f32x4;

__device__ __forceinline__ unsigned short f2bf(float f) {
    unsigned u = __float_as_uint(f);
    u = (u + 0x7fffu + ((u >> 16) & 1u)) >> 16;  // RNE
    return (unsigned short)u;
}
__device__ __forceinline__ float bflo(unsigned mv) { return __uint_as_float(mv << 16); }
__device__ __forceinline__ float bfhi(unsigned mv) { return __uint_as_float(mv & 0xffff0000u); }

__device__ __forceinline__ void gload_lds16(const unsigned short* g, unsigned short* l) {
    __builtin_amdgcn_global_load_lds((const __attribute__((address_space(1))) void*)g,
                                     (__attribute__((address_space(3))) void*)l, 16, 0, 0);
}

// ---- W (D,H) f32 -> Wt (H,D) bf16 (transpose + cast) ----
__global__ __launch_bounds__(256) void k_transpose(const float* __restrict__ W,
                                                   unsigned short* __restrict__ Wt) {
    __shared__ unsigned short tile[64][72];
    const int d0 = blockIdx.x * 64, h0 = blockIdx.y * 64;
    const int t = threadIdx.x;
    const int lr = t >> 6, lc = t & 63;
#pragma unroll
    for (int rr = 0; rr < 16; ++rr) {
        const int dl = rr * 4 + lr;
        tile[dl][lc] = f2bf(W[(size_t)(d0 + dl) * H_SZ + h0 + lc]);
    }
    __syncthreads();
#pragma unroll
    for (int rr = 0; rr < 16; ++rr) {
        const int hl = rr * 4 + lr;
        Wt[(size_t)(h0 + hl) * D_SZ + d0 + lc] = tile[lc][hl];
    }
}

// ---- xc = (x - c) bf16, xc2[b] = sum_d (x-c)^2 ----
__global__ __launch_bounds__(256) void k_prepx(const float* __restrict__ x, const float* __restrict__ c,
                                               unsigned short* __restrict__ xcbf, float* __restrict__ xc2) {
    const int b = blockIdx.x, t = threadIdx.x;
    const float* xr = x + (size_t)b * D_SZ;
    unsigned short* orow = xcbf + (size_t)b * D_SZ;
    float acc = 0.f;
#pragma unroll
    for (int ch = 0; ch < 2; ++ch) {
        const int base = (ch * 256 + t) * 8;
        const float4 v0 = *(const float4*)(xr + base);
        const float4 v1 = *(const float4*)(xr + base + 4);
        const float4 c0 = *(const float4*)(c + base);
        const float4 c1 = *(const float4*)(c + base + 4);
        const float e0 = v0.x - c0.x, e1 = v0.y - c0.y, e2 = v0.z - c0.z, e3 = v0.w - c0.w;
        const float e4 = v1.x - c1.x, e5 = v1.y - c1.y, e6 = v1.z - c1.z, e7 = v1.w - c1.w;
        acc += e0 * e0 + e1 * e1 + e2 * e2 + e3 * e3 + e4 * e4 + e5 * e5 + e6 * e6 + e7 * e7;
        short8 ov;
        ov[0] = (short)f2bf(e0); ov[1] = (short)f2bf(e1); ov[2] = (short)f2bf(e2); ov[3] = (short)f2bf(e3);
        ov[4] = (short)f2bf(e4); ov[5] = (short)f2bf(e5); ov[6] = (short)f2bf(e6); ov[7] = (short)f2bf(e7);
        *(short8*)(orow + base) = ov;
    }
#pragma unroll
    for (int off = 32; off > 0; off >>= 1) acc += __shfl_down(acc, off);
    __shared__ float wred[4];
    if ((t & 63) == 0) wred[t >> 6] = acc;
    __syncthreads();
    if (t == 0) xc2[b] = wred[0] + wred[1] + wred[2] + wred[3];
}

// ---- r = r0; mv = 0; rbfA = bf16(r0) ----
__global__ __launch_bounds__(256) void k_init(const float* __restrict__ r0, float* __restrict__ r,
                                              unsigned* __restrict__ mv,
                                              unsigned short* __restrict__ rbfA) {
    const size_t i = (size_t)blockIdx.x * 256 + threadIdx.x;
#pragma unroll
    for (int k = 0; k < 4; ++k) {
        const size_t idx = i + (size_t)k * 262144;
        const float val = r0[idx];
        r[idx] = val; mv[idx] = 0u; rbfA[idx] = f2bf(val);
    }
}

// ---- one-time TM x 64 tile bf16 MFMA GEMM (EPI 0: bf16 store; EPI 1: f32 store) ----
template <int TM, int EPI>
__global__ __launch_bounds__(256) void gemm64(
        const unsigned short* __restrict__ A, int lda,
        const unsigned short* __restrict__ Bt, int ldb, int K,
        unsigned short* __restrict__ Cb, float* __restrict__ Cf, int ldc) {
    __shared__ alignas(16) unsigned short Al[2][TM * 64];
    __shared__ alignas(16) unsigned short Bl[2][64 * 64];
    const int t = threadIdx.x, w = t >> 6, lane = t & 63;
    const int m0 = blockIdx.y * TM, n0 = blockIdx.x * 64;
    constexpr int NJ = (TM == 64) ? 2 : 1;
    const int row_base = (TM == 64) ? (w >> 1) * 32 : 0;
    const int col_base = (TM == 64) ? (w & 1) * 32 : w * 16;

    f32x4 acc[2][NJ] = {};

    auto stage = [&](int buf, int k0) {
#pragma unroll
        for (int h = 0; h < 2; ++h) {
            const int c = h * 256 + t;
            const int row = c >> 3, g = c & 7;
            const int gl = g ^ (row & 7);
            gload_lds16(Bt + (size_t)(n0 + row) * ldb + k0 + gl * 8, &Bl[buf][(h * 256 + w * 64) * 8]);
        }
        if constexpr (TM == 64) {
#pragma unroll
            for (int h = 0; h < 2; ++h) {
                const int c = h * 256 + t;
                const int row = c >> 3, g = c & 7;
                const int gl = g ^ (row & 7);
                gload_lds16(A + (size_t)(m0 + row) * lda + k0 + gl * 8, &Al[buf][(h * 256 + w * 64) * 8]);
            }
        } else {
            const int row = t >> 3, g = t & 7;
            const int gl = g ^ (row & 7);
            gload_lds16(A + (size_t)(m0 + row) * lda + k0 + gl * 8, &Al[buf][(w * 64) * 8]);
        }
    };

    stage(0, 0);
    const int nK = K >> 6;
    for (int kt = 0; kt < nK; ++kt) {
        __syncthreads();
        const int cur = kt & 1;
        if (kt + 1 < nK) stage(cur ^ 1, (kt + 1) << 6);
        const unsigned short* a_base = Al[cur];
        const unsigned short* b_base = Bl[cur];
#pragma unroll
        for (int kh = 0; kh < 2; ++kh) {
            short8 av[2], bv[NJ];
#pragma unroll
            for (int i = 0; i < 2; ++i) {
                const int row = row_base + i * 16 + (lane & 15);
                const int g = (kh * 4 + (lane >> 4)) ^ (row & 7);
                av[i] = *(const short8*)(a_base + row * 64 + g * 8);
            }
#pragma unroll
            for (int j = 0; j < NJ; ++j) {
                const int row = col_base + j * 16 + (lane & 15);
                const int g = (kh * 4 + (lane >> 4)) ^ (row & 7);
                bv[j] = *(const short8*)(b_base + row * 64 + g * 8);
            }
#pragma unroll
            for (int i = 0; i < 2; ++i)
#pragma unroll
                for (int j = 0; j < NJ; ++j)
                    acc[i][j] = __builtin_amdgcn_mfma_f32_16x16x32_bf16(av[i], bv[j], acc[i][j], 0, 0, 0);
        }
    }

#pragma unroll
    for (int i = 0; i < 2; ++i)
#pragma unroll
        for (int j = 0; j < NJ; ++j) {
            const int col = n0 + col_base + j * 16 + (lane & 15);
            const int row0 = m0 + row_base + i * 16 + ((lane >> 4) << 2);
#pragma unroll
            for (int q = 0; q < 4; ++q) {
                if constexpr (EPI == 0) Cb[(size_t)(row0 + q) * ldc + col] = f2bf(acc[i][j][q]);
                else Cf[(size_t)(row0 + q) * ldc + col] = acc[i][j][q];
            }
        }
}

// ---- loop GEMM: gemm64<64> clone with K-split 4. blockIdx.x = n_tile*4 + sp.
// Each block: 64x64 tile over K in [sp*512, sp*512+512), partial -> part[sp].
__global__ __launch_bounds__(256) void gemm_s(
        const unsigned short* __restrict__ Ain,   // bf16 r in (B_SZ x H)
        const unsigned short* __restrict__ G,     // bf16 G (H x H)
        float* __restrict__ part) {               // 4 planes of B_SZ x H f32
    __shared__ alignas(16) unsigned short Al[2][64 * 64];
    __shared__ alignas(16) unsigned short Bl[2][64 * 64];
    const int t = threadIdx.x, w = t >> 6, lane = t & 63;
    const int sp = blockIdx.x & 3;
    const int n0 = (blockIdx.x >> 2) * 64;
    const int m0 = blockIdx.y * 64;
    const int kb = sp * 512;
    float* pout = part + (size_t)sp * (B_SZ * H_SZ);
    const int row_base = (w >> 1) * 32;
    const int col_base = (w & 1) * 32;

    f32x4 acc[2][2] = {};

    auto stage = [&](int buf, int k0) {
#pragma unroll
        for (int h = 0; h < 2; ++h) {
            const int c = h * 256 + t;
            const int row = c >> 3, g = c & 7;
            const int gl = g ^ (row & 7);
            gload_lds16(G + (size_t)(n0 + row) * H_SZ + kb + k0 + gl * 8, &Bl[buf][(h * 256 + w * 64) * 8]);
            gload_lds16(Ain + (size_t)(m0 + row) * H_SZ + kb + k0 + gl * 8, &Al[buf][(h * 256 + w * 64) * 8]);
        }
    };

    stage(0, 0);
    for (int kt = 0; kt < 8; ++kt) {   // K=512, BK=64
        __syncthreads();
        const int cur = kt & 1;
        if (kt + 1 < 8) stage(cur ^ 1, (kt + 1) << 6);
        const unsigned short* a_base = Al[cur];
        const unsigned short* b_base = Bl[cur];
#pragma unroll
        for (int kh = 0; kh < 2; ++kh) {
            short8 av[2], bv[2];
#pragma unroll
            for (int i = 0; i < 2; ++i) {
                const int row = row_base + i * 16 + (lane & 15);
                av[i] = *(const short8*)(a_base + row * 64 + ((kh * 4 + (lane >> 4)) ^ (row & 7)) * 8);
            }
#pragma unroll
            for (int j = 0; j < 2; ++j) {
                const int row = col_base + j * 16 + (lane & 15);
                bv[j] = *(const short8*)(b_base + row * 64 + ((kh * 4 + (lane >> 4)) ^ (row & 7)) * 8);
            }
#pragma unroll
            for (int i = 0; i < 2; ++i)
#pragma unroll
                for (int j = 0; j < 2; ++j)
                    acc[i][j] = __builtin_amdgcn_mfma_f32_16x16x32_bf16(av[i], bv[j], acc[i][j], 0, 0, 0);
        }
    }

#pragma unroll
    for (int i = 0; i < 2; ++i)
#pragma unroll
        for (int j = 0; j < 2; ++j) {
            const int col = n0 + col_base + j * 16 + (lane & 15);
            const int row0 = m0 + row_base + i * 16 + ((lane >> 4) << 2);
#pragma unroll
            for (int q = 0; q < 4; ++q)
                pout[(size_t)(row0 + q) * H_SZ + col] = acc[i][j][q];
        }
}

// ---- k_adam: s = sum of 4 partials; fused Adam + loss. 8 elems/thread, vectorized.
__global__ __launch_bounds__(256) void k_adam(
        const float* __restrict__ part,
        const float* __restrict__ rin, float* __restrict__ rout,
        unsigned* __restrict__ mv,
        const float* __restrict__ ubuf, const float* __restrict__ bvec,
        unsigned short* __restrict__ rbf_out,     // null on last iter
        float* __restrict__ lossPart, float inv1, float inv2) {
    const int t = threadIdx.x, blk = blockIdx.x;
    const size_t base = ((size_t)blk * 256 + t) * 8;
    const int col = (int)(base & (H_SZ - 1));

    float s[8];
#pragma unroll
    for (int h = 0; h < 2; ++h) {
        float4 a0 = *(const float4*)(part + base + h * 4);
        float4 a1 = *(const float4*)(part + (size_t)(B_SZ * H_SZ) + base + h * 4);
        float4 a2 = *(const float4*)(part + (size_t)(2 * B_SZ * H_SZ) + base + h * 4);
        float4 a3 = *(const float4*)(part + (size_t)(3 * B_SZ * H_SZ) + base + h * 4);
        s[h * 4 + 0] = a0.x + a1.x + a2.x + a3.x;
        s[h * 4 + 1] = a0.y + a1.y + a2.y + a3.y;
        s[h * 4 + 2] = a0.z + a1.z + a2.z + a3.z;
        s[h * 4 + 3] = a0.w + a1.w + a2.w + a3.w;
    }
    float rv[8], uv[8], bv[8];
    unsigned mvv[8];
#pragma unroll
    for (int h = 0; h < 2; ++h) {
        *(float4*)(rv + h * 4) = *(const float4*)(rin + base + h * 4);
        *(float4*)(uv + h * 4) = *(const float4*)(ubuf + base + h * 4);
        *(float4*)(bv + h * 4) = *(const float4*)(bvec + col + h * 4);
        *(uint4*)(mvv + h * 4) = *(const uint4*)(mv + base + h * 4);
    }

    float lpart = 0.f;
    float ro[8];
    short8 rb;
#pragma unroll
    for (int e = 0; e < 8; ++e) {
        const float rold = rv[e], ue = uv[e], be = bv[e];
        const float g = (2.0f / B_SZ) * (rold - be - ue + s[e]);
        lpart += (rold - be) * (rold - be) + rold * (s[e] - 2.0f * ue);
        const float m1 = 0.9f * bflo(mvv[e]) + 0.1f * g;
        const float v1 = 0.999f * bfhi(mvv[e]) + 0.001f * (g * g);
        mvv[e] = (unsigned)f2bf(m1) | ((unsigned)f2bf(v1) << 16);
        const float rn = rold - 0.01f * (m1 * inv1) / (sqrtf(v1 * inv2) + 1e-8f);
        ro[e] = rn;
        rb[e] = (short)f2bf(rn);
    }
#pragma unroll
    for (int h = 0; h < 2; ++h) {
        *(uint4*)(mv + base + h * 4) = *(const uint4*)(mvv + h * 4);
        *(float4*)(rout + base + h * 4) = *(const float4*)(ro + h * 4);
    }
    if (rbf_out) *(short8*)(rbf_out + base) = rb;

#pragma unroll
    for (int off = 32; off > 0; off >>= 1) lpart += __shfl_down(lpart, off);
    __shared__ float wred[4];
    if ((t & 63) == 0) wred[t >> 6] = lpart;
    __syncthreads();
    if (t == 0) lossPart[blk] = wred[0] + wred[1] + wred[2] + wred[3];
}

// ---- losses[t] = (sum of 512 lossPart + sum_b xc2) / B ----
__global__ __launch_bounds__(256) void k_finalize(const float* __restrict__ lossPart,
                                                  const float* __restrict__ xc2, float* __restrict__ out) {
    const int it = blockIdx.x, t = threadIdx.x;
    float p = lossPart[it * 512 + t] + lossPart[it * 512 + 256 + t] + xc2[t] + xc2[t + 256];
#pragma unroll
    for (int off = 32; off > 0; off >>= 1) p += __shfl_down(p, off);
    __shared__ float wred[4];
    if ((t & 63) == 0) wred[t >> 6] = p;
    __syncthreads();
    if (t == 0) out[(size_t)B_SZ * H_SZ + it] = (wred[0] + wred[1] + wred[2] + wred[3]) * (1.0f / B_SZ);
}

extern "C" void kernel_launch(void* const* d_in, const int* in_sizes, int n_in,
                              void* d_out, int out_size, void* d_ws, size_t ws_size,
                              hipStream_t stream) {
    const float* x = (const float*)d_in[0];
    const float* W = (const float*)d_in[1];
    const float* cvec = (const float*)d_in[2];
    const float* bvec = (const float*)d_in[3];
    const float* r0 = (const float*)d_in[4];
    float* out = (float*)d_out;
    char* ws = (char*)d_ws;

    // part (16 MB, loop phase) aliases Wt (16 MB, setup phase) — stream-ordered.
    unsigned short* Wt = (unsigned short*)(ws);              // 16 MB   (H x D bf16)
    float* part = (float*)(ws);                              // 4 x B x H f32 partials
    unsigned short* Gbf = (unsigned short*)(ws + 16777216);  // 8 MB    (H x H bf16)
    unsigned short* xcbf = (unsigned short*)(ws + 25165824); // 4 MB    (B x D bf16)
    float* u = (float*)(ws + 29360128);                      // 4 MB    (B x H f32)
    float* r = (float*)(ws + 33554432);                      // 4 MB
    unsigned* mv = (unsigned*)(ws + 37748736);               // 4 MB    (bf16 m | bf16 v packed)
    unsigned short* rbfA = (unsigned short*)(ws + 41943040); // 2 MB
    unsigned short* rbfB = (unsigned short*)(ws + 44040192); // 2 MB
    float* xc2 = (float*)(ws + 46137344);                    // 2 KB
    float* lossPart = (float*)(ws + 46139392);               // 200 KB (ITERS x 512)

    k_transpose<<<dim3(64, 32), 256, 0, stream>>>(W, Wt);
    k_prepx<<<512, 256, 0, stream>>>(x, cvec, xcbf, xc2);
    k_init<<<1024, 256, 0, stream>>>(r0, r, mv, rbfA);
    // G = Wt @ Wt^T (W^T W), M=N=2048, K=4096 (1024 blocks, 4/CU)
    gemm64<64, 0><<<dim3(32, 32), 256, 0, stream>>>(Wt, D_SZ, Wt, D_SZ, D_SZ, Gbf, nullptr, H_SZ);
    // u = (x-c) @ W, M=512, N=2048, K=4096 (512 blocks, 2/CU)
    gemm64<32, 1><<<dim3(32, 16), 256, 0, stream>>>(xcbf, D_SZ, Wt, D_SZ, D_SZ, nullptr, u, H_SZ);

    for (int it = 0; it < ITERS; ++it) {
        const float inv1 = (float)(1.0 / (1.0 - std::pow(0.9, (double)(it + 1))));
        const float inv2 = (float)(1.0 / (1.0 - std::pow(0.999, (double)(it + 1))));
        const unsigned short* rin_bf = (it & 1) ? rbfB : rbfA;
        unsigned short* rout_bf = (it + 1 < ITERS) ? ((it & 1) ? rbfA : rbfB) : nullptr;
        float* rout_f = (it + 1 < ITERS) ? r : out;  // last iter writes f32 r into d_out
        gemm_s<<<dim3(128, 8), 256, 0, stream>>>(rin_bf, Gbf, part);
        k_adam<<<512, 256, 0, stream>>>(part, r, rout_f, mv, u, bvec, rout_bf,
                                        lossPart + (size_t)it * 512, inv1, inv2);
    }
    k_finalize<<<ITERS, 256, 0, stream>>>(lossPart, xc2, out);
}

// Round 16
// 1428.920 us; speedup vs baseline: 1.4392x; 1.4392x over previous
//
#include <hip/hip_runtime.h>
#include <cmath>

// Memory_76957224010242: 100-step Adam inference loop.
// G = W^T W, u = (x-c)@W once; per-iter s = r@G fused with Adam + loss.
// R15 = R14 with the 64-byte LDS overflow fixed: wred aliased into Ab scratch
// (Ab+Bb = 160 KB exactly; scratch use tops at ~70 KB, wred at float-ofs 20000).
// Pipeline: A(rbf, cross-XCD) 3-buf/2-deep, B(G, L2-local) 2-buf/1-deep,
// s_waitcnt vmcnt(2)+s_barrier per K-step (no full drain until last step).

#define B_SZ 512
#define H_SZ 2048
#define D_SZ 4096
#define ITERS 100

typedef __attribute__((ext_vector_type(8))) short short8;
typedef __attribute__((ext_vector_type(4))) float f32x4;

__device__ __forceinline__ unsigned short f2bf(float f) {
    unsigned u = __float_as_uint(f);
    u = (u + 0x7fffu + ((u >> 16) & 1u)) >> 16;  // RNE
    return (unsigned short)u;
}
__device__ __forceinline__ float bflo(unsigned mv) { return __uint_as_float(mv << 16); }
__device__ __forceinline__ float bfhi(unsigned mv) { return __uint_as_float(mv & 0xffff0000u); }

__device__ __forceinline__ void gload_lds16(const unsigned short* g, unsigned short* l) {
    __builtin_amdgcn_global_load_lds((const __attribute__((address_space(1))) void*)g,
                                     (__attribute__((address_space(3))) void*)l, 16, 0, 0);
}

// ---- W (D,H) f32 -> Wt (H,D) bf16 (transpose + cast) ----
__global__ __launch_bounds__(256) void k_transpose(const float* __restrict__ W,
                                                   unsigned short* __restrict__ Wt) {
    __shared__ unsigned short tile[64][72];
    const int d0 = blockIdx.x * 64, h0 = blockIdx.y * 64;
    const int t = threadIdx.x;
    const int lr = t >> 6, lc = t & 63;
#pragma unroll
    for (int rr = 0; rr < 16; ++rr) {
        const int dl = rr * 4 + lr;
        tile[dl][lc] = f2bf(W[(size_t)(d0 + dl) * H_SZ + h0 + lc]);
    }
    __syncthreads();
#pragma unroll
    for (int rr = 0; rr < 16; ++rr) {
        const int hl = rr * 4 + lr;
        Wt[(size_t)(h0 + hl) * D_SZ + d0 + lc] = tile[lc][hl];
    }
}

// ---- xc = (x - c) bf16, xc2[b] = sum_d (x-c)^2 ----
__global__ __launch_bounds__(256) void k_prepx(const float* __restrict__ x, const float* __restrict__ c,
                                               unsigned short* __restrict__ xcbf, float* __restrict__ xc2) {
    const int b = blockIdx.x, t = threadIdx.x;
    const float* xr = x + (size_t)b * D_SZ;
    unsigned short* orow = xcbf + (size_t)b * D_SZ;
    float acc = 0.f;
#pragma unroll
    for (int ch = 0; ch < 2; ++ch) {
        const int base = (ch * 256 + t) * 8;
        const float4 v0 = *(const float4*)(xr + base);
        const float4 v1 = *(const float4*)(xr + base + 4);
        const float4 c0 = *(const float4*)(c + base);
        const float4 c1 = *(const float4*)(c + base + 4);
        const float e0 = v0.x - c0.x, e1 = v0.y - c0.y, e2 = v0.z - c0.z, e3 = v0.w - c0.w;
        const float e4 = v1.x - c1.x, e5 = v1.y - c1.y, e6 = v1.z - c1.z, e7 = v1.w - c1.w;
        acc += e0 * e0 + e1 * e1 + e2 * e2 + e3 * e3 + e4 * e4 + e5 * e5 + e6 * e6 + e7 * e7;
        short8 ov;
        ov[0] = (short)f2bf(e0); ov[1] = (short)f2bf(e1); ov[2] = (short)f2bf(e2); ov[3] = (short)f2bf(e3);
        ov[4] = (short)f2bf(e4); ov[5] = (short)f2bf(e5); ov[6] = (short)f2bf(e6); ov[7] = (short)f2bf(e7);
        *(short8*)(orow + base) = ov;
    }
#pragma unroll
    for (int off = 32; off > 0; off >>= 1) acc += __shfl_down(acc, off);
    __shared__ float wred[4];
    if ((t & 63) == 0) wred[t >> 6] = acc;
    __syncthreads();
    if (t == 0) xc2[b] = wred[0] + wred[1] + wred[2] + wred[3];
}

// ---- r = r0; mv = 0; rbfA = bf16(r0) ----
__global__ __launch_bounds__(256) void k_init(const float* __restrict__ r0, float* __restrict__ r,
                                              unsigned* __restrict__ mv,
                                              unsigned short* __restrict__ rbfA) {
    const size_t i = (size_t)blockIdx.x * 256 + threadIdx.x;
#pragma unroll
    for (int k = 0; k < 4; ++k) {
        const size_t idx = i + (size_t)k * 262144;
        const float val = r0[idx];
        r[idx] = val; mv[idx] = 0u; rbfA[idx] = f2bf(val);
    }
}

// ---- one-time TM x 64 tile bf16 MFMA GEMM (EPI 0: bf16 store; EPI 1: f32 store) ----
template <int TM, int EPI>
__global__ __launch_bounds__(256) void gemm64(
        const unsigned short* __restrict__ A, int lda,
        const unsigned short* __restrict__ Bt, int ldb, int K,
        unsigned short* __restrict__ Cb, float* __restrict__ Cf, int ldc) {
    __shared__ alignas(16) unsigned short Al[2][TM * 64];
    __shared__ alignas(16) unsigned short Bl[2][64 * 64];
    const int t = threadIdx.x, w = t >> 6, lane = t & 63;
    const int m0 = blockIdx.y * TM, n0 = blockIdx.x * 64;
    constexpr int NJ = (TM == 64) ? 2 : 1;
    const int row_base = (TM == 64) ? (w >> 1) * 32 : 0;
    const int col_base = (TM == 64) ? (w & 1) * 32 : w * 16;

    f32x4 acc[2][NJ] = {};

    auto stage = [&](int buf, int k0) {
#pragma unroll
        for (int h = 0; h < 2; ++h) {
            const int c = h * 256 + t;
            const int row = c >> 3, g = c & 7;
            const int gl = g ^ (row & 7);
            gload_lds16(Bt + (size_t)(n0 + row) * ldb + k0 + gl * 8, &Bl[buf][(h * 256 + w * 64) * 8]);
        }
        if constexpr (TM == 64) {
#pragma unroll
            for (int h = 0; h < 2; ++h) {
                const int c = h * 256 + t;
                const int row = c >> 3, g = c & 7;
                const int gl = g ^ (row & 7);
                gload_lds16(A + (size_t)(m0 + row) * lda + k0 + gl * 8, &Al[buf][(h * 256 + w * 64) * 8]);
            }
        } else {
            const int row = t >> 3, g = t & 7;
            const int gl = g ^ (row & 7);
            gload_lds16(A + (size_t)(m0 + row) * lda + k0 + gl * 8, &Al[buf][(w * 64) * 8]);
        }
    };

    stage(0, 0);
    const int nK = K >> 6;
    for (int kt = 0; kt < nK; ++kt) {
        __syncthreads();
        const int cur = kt & 1;
        if (kt + 1 < nK) stage(cur ^ 1, (kt + 1) << 6);
        const unsigned short* a_base = Al[cur];
        const unsigned short* b_base = Bl[cur];
#pragma unroll
        for (int kh = 0; kh < 2; ++kh) {
            short8 av[2], bv[NJ];
#pragma unroll
            for (int i = 0; i < 2; ++i) {
                const int row = row_base + i * 16 + (lane & 15);
                const int g = (kh * 4 + (lane >> 4)) ^ (row & 7);
                av[i] = *(const short8*)(a_base + row * 64 + g * 8);
            }
#pragma unroll
            for (int j = 0; j < NJ; ++j) {
                const int row = col_base + j * 16 + (lane & 15);
                const int g = (kh * 4 + (lane >> 4)) ^ (row & 7);
                bv[j] = *(const short8*)(b_base + row * 64 + g * 8);
            }
#pragma unroll
            for (int i = 0; i < 2; ++i)
#pragma unroll
                for (int j = 0; j < NJ; ++j)
                    acc[i][j] = __builtin_amdgcn_mfma_f32_16x16x32_bf16(av[i], bv[j], acc[i][j], 0, 0, 0);
        }
    }

#pragma unroll
    for (int i = 0; i < 2; ++i)
#pragma unroll
        for (int j = 0; j < NJ; ++j) {
            const int col = n0 + col_base + j * 16 + (lane & 15);
            const int row0 = m0 + row_base + i * 16 + ((lane >> 4) << 2);
#pragma unroll
            for (int q = 0; q < 4; ++q) {
                if constexpr (EPI == 0) Cb[(size_t)(row0 + q) * ldc + col] = f2bf(acc[i][j][q]);
                else Cf[(size_t)(row0 + q) * ldc + col] = acc[i][j][q];
            }
        }
}

// ---- loop kernel: R12 structure + counted-vmcnt pipeline.
// 64x64 tile, 16 waves, 256 blocks. Wave = (quadrant qd = w&3) x (K-group gr = w>>2).
// A: 3 buffers, 2-deep prefetch. B: 2 buffers, 1-deep. Wait = vmcnt(2)+lgkmcnt(0).
__global__ __launch_bounds__(1024) void gemm_q(
        const unsigned short* __restrict__ Ain,   // bf16 r in (B_SZ x H)
        const unsigned short* __restrict__ G,     // bf16 G (H x H)
        const float* __restrict__ rin,
        float* __restrict__ rout,
        unsigned* __restrict__ mv,
        const float* __restrict__ ubuf,
        const float* __restrict__ bvec,
        unsigned short* __restrict__ rbf_out,     // null on last iter
        float* __restrict__ lossPart,
        float inv1, float inv2) {
    __shared__ alignas(16) unsigned short Ab[3][4][4096];  // 96 KB: A, 3-buf x 4 groups
    __shared__ alignas(16) unsigned short Bb[2][4][4096];  // 64 KB: B, 2-buf x 4 groups
    // LDS total = 160 KB exactly. Loss-reduction wred aliased into Ab scratch below.
    const int t = threadIdx.x, w = t >> 6, lane = t & 63;
    const int bid = blockIdx.x;
    const int m0 = (bid >> 5) * 64;
    const int n0 = ((bid & 7) * 4 + ((bid >> 3) & 3)) * 64;   // XCD-pinned G panels
    const int qd = w & 3, gr = w >> 2;
    const int qrow = (qd >> 1) * 32, qcol = (qd & 1) * 32;
    const int rlo = lane & 15, hi = lane >> 4;

    // ---- epilogue-state prefetch (oldest in vmcnt FIFO; drained at step 0) ----
    const int col0 = n0 + qcol + (gr & 1) * 16 + rlo;
    const int rowb = m0 + qrow + (gr >> 1) * 16 + (hi << 2);
    float pre_r[4], pre_u[4];
    unsigned pre_mv[4];
    const float pre_b = bvec[col0];
#pragma unroll
    for (int q = 0; q < 4; ++q) {
        const size_t idx = (size_t)(rowb + q) * H_SZ + col0;
        pre_r[q] = rin[idx]; pre_u[q] = ubuf[idx]; pre_mv[q] = mv[idx];
    }
    __builtin_amdgcn_sched_barrier(0);

    // ---- staging: each group stages its own K-range; 2 loads/thread per stage ----
    const int tt = t & 255;
    auto stageA = [&](int buf, int s) {
        const int kbase = gr * 512 + s * 64;
#pragma unroll
        for (int c = 0; c < 2; ++c) {
            const int idx = c * 256 + tt;
            const int row = idx >> 3, g = idx & 7;
            const int gl = g ^ (row & 7);
            gload_lds16(Ain + (size_t)(m0 + row) * H_SZ + kbase + gl * 8, &Ab[buf][gr][idx * 8]);
        }
    };
    auto stageB = [&](int buf, int s) {
        const int kbase = gr * 512 + s * 64;
#pragma unroll
        for (int c = 0; c < 2; ++c) {
            const int idx = c * 256 + tt;
            const int row = idx >> 3, g = idx & 7;
            const int gl = g ^ (row & 7);
            gload_lds16(G + (size_t)(n0 + row) * H_SZ + kbase + gl * 8, &Bb[buf][gr][idx * 8]);
        }
    };

    // prologue FIFO: [epi..., A0, B0, A1]
    stageA(0, 0); stageB(0, 0); stageA(1, 1);

    f32x4 acc[2][2] = {};
    for (int s = 0; s < 8; ++s) {
        // steady: drain thru B(s) (leaves A(s+1)'s 2 loads); last step drains all.
        if (s < 7) asm volatile("s_waitcnt vmcnt(2) lgkmcnt(0)" ::: "memory");
        else       asm volatile("s_waitcnt vmcnt(0) lgkmcnt(0)" ::: "memory");
        __builtin_amdgcn_s_barrier();
        __builtin_amdgcn_sched_barrier(0);
        if (s + 1 < 8) stageB((s + 1) & 1, s + 1);
        if (s + 2 < 8) stageA((s + 2) % 3, s + 2);
        const unsigned short* a_base = Ab[s % 3][gr];
        const unsigned short* b_base = Bb[s & 1][gr];
#pragma unroll
        for (int kh = 0; kh < 2; ++kh) {
            short8 av[2], bv[2];
#pragma unroll
            for (int i = 0; i < 2; ++i) {
                const int row = qrow + i * 16 + rlo;
                av[i] = *(const short8*)(a_base + row * 64 + ((kh * 4 + hi) ^ (row & 7)) * 8);
            }
#pragma unroll
            for (int j = 0; j < 2; ++j) {
                const int row = qcol + j * 16 + rlo;
                bv[j] = *(const short8*)(b_base + row * 64 + ((kh * 4 + hi) ^ (row & 7)) * 8);
            }
#pragma unroll
            for (int i = 0; i < 2; ++i)
#pragma unroll
                for (int j = 0; j < 2; ++j)
                    acc[i][j] = __builtin_amdgcn_mfma_f32_16x16x32_bf16(av[i], bv[j], acc[i][j], 0, 0, 0);
        }
    }

    // ---- K-reduction via LDS scratch (aliases Ab; stride 17: gcd(17,32)=1).
    // Max scratch index (1023*17+15) = 17406 floats; wred at ofs 20000 (Ab holds 24576 floats).
    __syncthreads();  // all reads + staged writes complete before overwrite
    float* scr = (float*)Ab;
    float* wred = scr + 20000;
    const int wbase = (w * 64 + lane) * 17;
#pragma unroll
    for (int i = 0; i < 2; ++i)
#pragma unroll
        for (int j = 0; j < 2; ++j)
#pragma unroll
            for (int q = 0; q < 4; ++q)
                scr[wbase + (i * 2 + j) * 4 + q] = acc[i][j][q];
    __syncthreads();

    float sval[4];
#pragma unroll
    for (int q = 0; q < 4; ++q) {
        float s = 0.f;
#pragma unroll
        for (int g = 0; g < 4; ++g)
            s += scr[((g * 4 + qd) * 64 + lane) * 17 + gr * 4 + q];
        sval[q] = s;
    }

    // ---- fused Adam + loss (state already in registers) ----
    float lpart = 0.f;
#pragma unroll
    for (int q = 0; q < 4; ++q) {
        const size_t idx = (size_t)(rowb + q) * H_SZ + col0;
        const float s = sval[q];
        const float rold = pre_r[q];
        const float ue = pre_u[q];
        const float g = (2.0f / B_SZ) * (rold - pre_b - ue + s);
        lpart += (rold - pre_b) * (rold - pre_b) + rold * (s - 2.0f * ue);
        const float m1 = 0.9f * bflo(pre_mv[q]) + 0.1f * g;
        const float v1 = 0.999f * bfhi(pre_mv[q]) + 0.001f * (g * g);
        mv[idx] = (unsigned)f2bf(m1) | ((unsigned)f2bf(v1) << 16);
        const float rn = rold - 0.01f * (m1 * inv1) / (sqrtf(v1 * inv2) + 1e-8f);
        rout[idx] = rn;
        if (rbf_out) rbf_out[idx] = f2bf(rn);
    }
#pragma unroll
    for (int off = 32; off > 0; off >>= 1) lpart += __shfl_down(lpart, off);
    if (lane == 0) wred[w] = lpart;
    __syncthreads();
    if (t == 0) {
        float sum = 0.f;
#pragma unroll
        for (int k = 0; k < 16; ++k) sum += wred[k];
        lossPart[bid] = sum;
    }
}

// ---- losses[t] = (sum of 256 lossPart + sum_b xc2) / B ----
__global__ __launch_bounds__(256) void k_finalize(const float* __restrict__ lossPart,
                                                  const float* __restrict__ xc2, float* __restrict__ out) {
    const int it = blockIdx.x, t = threadIdx.x;
    float p = lossPart[it * 256 + t] + xc2[t] + xc2[t + 256];
#pragma unroll
    for (int off = 32; off > 0; off >>= 1) p += __shfl_down(p, off);
    __shared__ float wred[4];
    if ((t & 63) == 0) wred[t >> 6] = p;
    __syncthreads();
    if (t == 0) out[(size_t)B_SZ * H_SZ + it] = (wred[0] + wred[1] + wred[2] + wred[3]) * (1.0f / B_SZ);
}

extern "C" void kernel_launch(void* const* d_in, const int* in_sizes, int n_in,
                              void* d_out, int out_size, void* d_ws, size_t ws_size,
                              hipStream_t stream) {
    const float* x = (const float*)d_in[0];
    const float* W = (const float*)d_in[1];
    const float* cvec = (const float*)d_in[2];
    const float* bvec = (const float*)d_in[3];
    const float* r0 = (const float*)d_in[4];
    float* out = (float*)d_out;
    char* ws = (char*)d_ws;

    unsigned short* Wt = (unsigned short*)(ws);              // 16 MB   (H x D bf16)
    unsigned short* Gbf = (unsigned short*)(ws + 16777216);  // 8 MB    (H x H bf16)
    unsigned short* xcbf = (unsigned short*)(ws + 25165824); // 4 MB    (B x D bf16)
    float* u = (float*)(ws + 29360128);                      // 4 MB    (B x H f32)
    float* r = (float*)(ws + 33554432);                      // 4 MB
    unsigned* mv = (unsigned*)(ws + 37748736);               // 4 MB    (bf16 m | bf16 v packed)
    unsigned short* rbfA = (unsigned short*)(ws + 41943040); // 2 MB
    unsigned short* rbfB = (unsigned short*)(ws + 44040192); // 2 MB
    float* xc2 = (float*)(ws + 46137344);                    // 2 KB
    float* lossPart = (float*)(ws + 46139392);               // 100 KB (ITERS x 256)

    k_transpose<<<dim3(64, 32), 256, 0, stream>>>(W, Wt);
    k_prepx<<<512, 256, 0, stream>>>(x, cvec, xcbf, xc2);
    k_init<<<1024, 256, 0, stream>>>(r0, r, mv, rbfA);
    // G = Wt @ Wt^T (W^T W), M=N=2048, K=4096 (1024 blocks, 4/CU)
    gemm64<64, 0><<<dim3(32, 32), 256, 0, stream>>>(Wt, D_SZ, Wt, D_SZ, D_SZ, Gbf, nullptr, H_SZ);
    // u = (x-c) @ W, M=512, N=2048, K=4096 (512 blocks, 2/CU)
    gemm64<32, 1><<<dim3(32, 16), 256, 0, stream>>>(xcbf, D_SZ, Wt, D_SZ, D_SZ, nullptr, u, H_SZ);

    for (int it = 0; it < ITERS; ++it) {
        const float inv1 = (float)(1.0 / (1.0 - std::pow(0.9, (double)(it + 1))));
        const float inv2 = (float)(1.0 / (1.0 - std::pow(0.999, (double)(it + 1))));
        const unsigned short* rin_bf = (it & 1) ? rbfB : rbfA;
        unsigned short* rout_bf = (it + 1 < ITERS) ? ((it & 1) ? rbfA : rbfB) : nullptr;
        float* rout_f = (it + 1 < ITERS) ? r : out;  // last iter writes f32 r into d_out
        gemm_q<<<256, 1024, 0, stream>>>(rin_bf, Gbf, r, rout_f, mv, u, bvec, rout_bf,
                                         lossPart + (size_t)it * 256, inv1, inv2);
    }
    k_finalize<<<ITERS, 256, 0, stream>>>(lossPart, xc2, out);
}